// Round 1
// baseline (131.128 us; speedup 1.0000x reference)
//
#include <hip/hip_runtime.h>
#include <cstdint>
#include <cstddef>

#define BB 8
#define CC 128
#define HH 96
#define WW 320
#define HW (HH*WW)        // 30720
#define NSEL 32
#define NSELH 16

__device__ __forceinline__ float sigmoidf_(float x) {
  return 1.0f / (1.0f + __expf(-x));
}

// K1: copy x -> out (all channels) + per-(b,c) partial sums T, A, Q in f64.
__global__ __launch_bounds__(256) void k_copy_reduce(
    const float* __restrict__ x, float* __restrict__ out,
    double* __restrict__ partials) {
  int bc = blockIdx.x;  // b*CC + c
  const float4* __restrict__ xi = (const float4*)(x + (size_t)bc * HW);
  float4* __restrict__ oi = (float4*)(out + (size_t)bc * HW);
  double t = 0.0, a = 0.0, q = 0.0;
  for (int j = threadIdx.x; j < HW/4; j += 256) {
    float4 v = xi[j];
    oi[j] = v;
    int h = j / (WW/4);
    double d = 0.1 + (double)h * (0.9/95.0);
    float s0 = sigmoidf_(v.x), s1 = sigmoidf_(v.y);
    float s2 = sigmoidf_(v.z), s3 = sigmoidf_(v.w);
    double ts = (double)((s0+s1)+(s2+s3));
    t += ts;
    a += ts * d;
    q += (double)((s0*s0+s1*s1)+(s2*s2+s3*s3));
  }
  __shared__ double sh[3][256];
  sh[0][threadIdx.x]=t; sh[1][threadIdx.x]=a; sh[2][threadIdx.x]=q;
  __syncthreads();
  for (int ofs=128; ofs>0; ofs>>=1) {
    if ((int)threadIdx.x < ofs) {
      sh[0][threadIdx.x]+=sh[0][threadIdx.x+ofs];
      sh[1][threadIdx.x]+=sh[1][threadIdx.x+ofs];
      sh[2][threadIdx.x]+=sh[2][threadIdx.x+ofs];
    }
    __syncthreads();
  }
  if (threadIdx.x==0) {
    partials[bc*3+0]=sh[0][0];
    partials[bc*3+1]=sh[1][0];
    partials[bc*3+2]=sh[2][0];
  }
}

// K2: reduce partials over b, compute the two cos rankings, emit idx[32].
__global__ __launch_bounds__(CC) void k_select(
    const double* __restrict__ partials, int* __restrict__ idx) {
  int c = threadIdx.x;
  double T=0.0, A=0.0, Q=0.0;
  for (int b=0;b<BB;b++) {
    int bc = b*CC + c;
    T += partials[bc*3+0];
    A += partials[bc*3+1];
    Q += partials[bc*3+2];
  }
  double sn = sqrt(Q); if (sn < 1e-6) sn = 1e-6;
  double c1 = A / sn;
  double c2 = (T - A) / sn;
  __shared__ double s1[CC], s2[CC];
  s1[c]=c1; s2[c]=c2;
  __syncthreads();
  int r1=0, r2=0;
  for (int j=0;j<CC;j++) {
    r1 += (s1[j] > c1) || (s1[j]==c1 && j<c);
    r2 += (s2[j] > c2) || (s2[j]==c2 && j<c);
  }
  if (r1 < NSELH) idx[r1] = c;
  if (r2 < NSELH) idx[NSELH + r2] = c;
}

// K3: closed-form scan: per column, k[h] = min(run-of-masked starting at h
// (stopping at H-1), 32); prop row = h + k[h].
__global__ __launch_bounds__(WW) void k_runs(
    const int* __restrict__ mask, uint8_t* __restrict__ kk) {
  int b = blockIdx.x;
  int w = threadIdx.x;
  const int* mcol = mask + (size_t)b*HW + w;
  uint8_t* kcol = kk + (size_t)b*HW + w;
  int jstar = 0;
  kcol[(HH-1)*WW] = 0;
  for (int h = HH-2; h >= 0; --h) {
    int m = mcol[h*WW];
    jstar = m ? (jstar + 1) : 0;
    kcol[h*WW] = (uint8_t)(jstar < 32 ? jstar : 32);
  }
}

// K4: per-(b,selc) max |prop-sel| -> mclip = max*0.3 (0 -> 1).
__global__ __launch_bounds__(256) void k_maxdiff(
    const float* __restrict__ x, const int* __restrict__ idx,
    const uint8_t* __restrict__ kk, float* __restrict__ mclip) {
  int b = blockIdx.x >> 5;
  int c = blockIdx.x & 31;
  int ic = idx[c];
  const float* __restrict__ base = x + ((size_t)b*CC + ic)*HW;
  const uint8_t* __restrict__ kb = kk + (size_t)b*HW;
  float mx = 0.0f;
  for (int e = threadIdx.x; e < HW; e += 256) {
    int h = e / WW, w = e - h*WW;
    float sel = base[e];
    int r = h + (int)kb[e];
    float prop = base[r*WW + w];
    mx = fmaxf(mx, fabsf(prop - sel));
  }
  __shared__ float sh[256];
  sh[threadIdx.x]=mx; __syncthreads();
  for (int ofs=128; ofs>0; ofs>>=1) {
    if ((int)threadIdx.x<ofs) sh[threadIdx.x]=fmaxf(sh[threadIdx.x], sh[threadIdx.x+ofs]);
    __syncthreads();
  }
  if (threadIdx.x==0) {
    float m = sh[0] * 0.3f;
    if (m == 0.0f) m = 1.0f;
    mclip[blockIdx.x] = m;
  }
}

// K5: final fused pass: w = max_c clip(|prop-sel|/mclip_c, 0, 1);
// refined = w*prop + (1-w)*sel; overwrite selected channels of out.
__global__ __launch_bounds__(WW) void k_refine(
    const float* __restrict__ x, const int* __restrict__ idx,
    const uint8_t* __restrict__ kk, const float* __restrict__ mclip,
    float* __restrict__ out) {
  int bh = blockIdx.x;
  int b = bh / HH, h = bh - b*HH;
  int w = threadIdx.x;
  __shared__ int sidx[NSEL];
  __shared__ float smc[NSEL];
  if (threadIdx.x < NSEL) {
    sidx[threadIdx.x] = idx[threadIdx.x];
    smc[threadIdx.x]  = mclip[b*NSEL + threadIdx.x];
  }
  __syncthreads();
  int r = h + (int)kk[(size_t)bh*WW + w];
  float sel[NSEL], prop[NSEL];
  float wmax = 0.0f;
  #pragma unroll
  for (int c=0;c<NSEL;c++) {
    const float* __restrict__ base = x + ((size_t)b*CC + sidx[c])*HW;
    sel[c]  = base[h*WW + w];
    prop[c] = base[r*WW + w];
    float v = fabsf(prop[c]-sel[c]) / smc[c];
    wmax = fmaxf(wmax, fminf(v, 1.0f));
  }
  #pragma unroll
  for (int c=0;c<NSEL;c++) {
    float rf = wmax*prop[c] + (1.0f - wmax)*sel[c];
    out[((size_t)b*CC + sidx[c])*HW + h*WW + w] = rf;
  }
}

extern "C" void kernel_launch(void* const* d_in, const int* in_sizes, int n_in,
                              void* d_out, int out_size, void* d_ws, size_t ws_size,
                              hipStream_t stream) {
  const float* x   = (const float*)d_in[0];
  const int* mask  = (const int*)d_in[1];
  float* out       = (float*)d_out;

  char* ws = (char*)d_ws;
  double* partials = (double*)(ws);                 // 1024*3*8 = 24576 B
  int*    idx      = (int*)(ws + 24576);            // 128 B
  float*  mclip    = (float*)(ws + 24576 + 128);    // 1024 B
  uint8_t* kk      = (uint8_t*)(ws + 24576 + 128 + 1024); // 245760 B

  k_copy_reduce<<<BB*CC, 256, 0, stream>>>(x, out, partials);
  k_select<<<1, CC, 0, stream>>>(partials, idx);
  k_runs<<<BB, WW, 0, stream>>>(mask, kk);
  k_maxdiff<<<BB*NSEL, 256, 0, stream>>>(x, idx, kk, mclip);
  k_refine<<<BB*HH, WW, 0, stream>>>(x, idx, kk, mclip, out);
}

// Round 2
// 103.420 us; speedup vs baseline: 1.2679x; 1.2679x over previous
//
#include <hip/hip_runtime.h>
#include <cstdint>
#include <cstddef>

#define BB 8
#define CC 128
#define HH 96
#define WW 320
#define HW (HH*WW)        // 30720
#define NSEL 32
#define NSELH 16
#define U1 6

__device__ __forceinline__ float sigmoidf_(float x) {
  // approx rcp (1 ulp) instead of precise div sequence; selection gaps ~5e-6
  // dwarf the ~1e-7 relative error this introduces.
  return __builtin_amdgcn_rcpf(1.0f + __expf(-x));
}

// K1: copy x -> out (all channels) + per-(b,c) partial sums T, A, Q.
// Manual unroll x6 keeps 6 float4 loads in flight per wave (MLP fix).
__global__ __launch_bounds__(256) void k_copy_reduce(
    const float* __restrict__ x, float* __restrict__ out,
    double* __restrict__ partials) {
  int bc = blockIdx.x;  // b*CC + c
  const float4* __restrict__ xi = (const float4*)(x + (size_t)bc * HW);
  float4* __restrict__ oi = (float4*)(out + (size_t)bc * HW);
  int t = threadIdx.x;
  float tf = 0.0f, af = 0.0f, qf = 0.0f;
  // HW/4 = 7680 = 5 * (256*6)
  for (int base = 0; base < HW/4; base += 256*U1) {
    float4 v[U1];
    #pragma unroll
    for (int u = 0; u < U1; u++) v[u] = xi[base + u*256 + t];
    #pragma unroll
    for (int u = 0; u < U1; u++) {
      int j = base + u*256 + t;
      oi[j] = v[u];
      int h = j / (WW/4);
      float d = 0.1f + (float)h * (0.9f/95.0f);
      float s0 = sigmoidf_(v[u].x), s1 = sigmoidf_(v[u].y);
      float s2 = sigmoidf_(v[u].z), s3 = sigmoidf_(v[u].w);
      float ts = (s0+s1)+(s2+s3);
      tf += ts;
      af += ts * d;
      qf += (s0*s0+s1*s1)+(s2*s2+s3*s3);
    }
  }
  __shared__ double sh[3][256];
  sh[0][t]=(double)tf; sh[1][t]=(double)af; sh[2][t]=(double)qf;
  __syncthreads();
  for (int ofs=128; ofs>0; ofs>>=1) {
    if (t < ofs) {
      sh[0][t]+=sh[0][t+ofs];
      sh[1][t]+=sh[1][t+ofs];
      sh[2][t]+=sh[2][t+ofs];
    }
    __syncthreads();
  }
  if (t==0) {
    partials[bc*3+0]=sh[0][0];
    partials[bc*3+1]=sh[1][0];
    partials[bc*3+2]=sh[2][0];
  }
}

// K2: reduce partials over b, compute the two cos rankings, emit idx[32].
__global__ __launch_bounds__(CC) void k_select(
    const double* __restrict__ partials, int* __restrict__ idx) {
  int c = threadIdx.x;
  double T=0.0, A=0.0, Q=0.0;
  for (int b=0;b<BB;b++) {
    int bc = b*CC + c;
    T += partials[bc*3+0];
    A += partials[bc*3+1];
    Q += partials[bc*3+2];
  }
  double sn = sqrt(Q); if (sn < 1e-6) sn = 1e-6;
  double c1 = A / sn;
  double c2 = (T - A) / sn;
  __shared__ double s1[CC], s2[CC];
  s1[c]=c1; s2[c]=c2;
  __syncthreads();
  int r1=0, r2=0;
  for (int j=0;j<CC;j++) {
    r1 += (s1[j] > c1) || (s1[j]==c1 && j<c);
    r2 += (s2[j] > c2) || (s2[j]==c2 && j<c);
  }
  if (r1 < NSELH) idx[r1] = c;
  if (r2 < NSELH) idx[NSELH + r2] = c;
}

// K3: parallel closed-form runs. k[h] = min(consecutive 1s in mask[h..94], 32);
// build a 96-bit column bitmask (95 independent pipelined loads), then ctz.
__global__ __launch_bounds__(64) void k_runs(
    const int* __restrict__ mask, uint8_t* __restrict__ kk) {
  int b = blockIdx.x / 5;
  int w = (blockIdx.x % 5)*64 + threadIdx.x;
  const int* __restrict__ mcol = mask + (size_t)b*HW + w;
  unsigned long long lo=0ull, hi=0ull;
  #pragma unroll
  for (int h=0; h<64; ++h) lo |= (unsigned long long)(mcol[h*WW]!=0) << h;
  #pragma unroll
  for (int h=64; h<95; ++h) hi |= (unsigned long long)(mcol[h*WW]!=0) << (h-64);
  // row 95 bit stays 0 -> runs stop at the last row, matching the scan.
  uint8_t* __restrict__ kcol = kk + (size_t)b*HW + w;
  #pragma unroll
  for (int h=0; h<96; ++h) {
    unsigned long long s;
    if (h == 0)      s = lo;
    else if (h < 64) s = (lo >> h) | (hi << (64-h));
    else             s = hi >> (h-64);
    // only low 33 bits matter (cap 32); sentinel bit keeps ctz defined.
    int run = __builtin_ctzll(~s | (1ull<<33));
    kcol[h*WW] = (uint8_t)(run > 32 ? 32 : run);
  }
}

// K4: per-(b,selc) max |prop-sel| -> mclip = max*0.3 (0 -> 1).
__global__ __launch_bounds__(256) void k_maxdiff(
    const float* __restrict__ x, const int* __restrict__ idx,
    const uint8_t* __restrict__ kk, float* __restrict__ mclip) {
  int b = blockIdx.x >> 5;
  int c = blockIdx.x & 31;
  int ic = idx[c];
  const float* __restrict__ base = x + ((size_t)b*CC + ic)*HW;
  const uint8_t* __restrict__ kb = kk + (size_t)b*HW;
  float mx = 0.0f;
  for (int j = threadIdx.x; j < HW/4; j += 256) {
    float4 sel = ((const float4*)base)[j];
    uchar4 kv  = ((const uchar4*)kb)[j];
    int h = j / (WW/4);
    int w4 = (j - h*(WW/4))*4;
    float p0 = base[(h+(int)kv.x)*WW + w4+0];
    float p1 = base[(h+(int)kv.y)*WW + w4+1];
    float p2 = base[(h+(int)kv.z)*WW + w4+2];
    float p3 = base[(h+(int)kv.w)*WW + w4+3];
    mx = fmaxf(mx, fmaxf(fmaxf(fabsf(p0-sel.x), fabsf(p1-sel.y)),
                         fmaxf(fabsf(p2-sel.z), fabsf(p3-sel.w))));
  }
  __shared__ float sh[256];
  sh[threadIdx.x]=mx; __syncthreads();
  for (int ofs=128; ofs>0; ofs>>=1) {
    if ((int)threadIdx.x<ofs) sh[threadIdx.x]=fmaxf(sh[threadIdx.x], sh[threadIdx.x+ofs]);
    __syncthreads();
  }
  if (threadIdx.x==0) {
    float m = sh[0] * 0.3f;
    if (m == 0.0f) m = 1.0f;
    mclip[blockIdx.x] = m;
  }
}

// K5: w = max_c clip(|prop-sel|/mclip_c, 0, 1); refined = w*prop + (1-w)*sel.
__global__ __launch_bounds__(WW) void k_refine(
    const float* __restrict__ x, const int* __restrict__ idx,
    const uint8_t* __restrict__ kk, const float* __restrict__ mclip,
    float* __restrict__ out) {
  int bh = blockIdx.x;
  int b = bh / HH, h = bh - b*HH;
  int w = threadIdx.x;
  __shared__ int sidx[NSEL];
  __shared__ float smc[NSEL];
  if (threadIdx.x < NSEL) {
    sidx[threadIdx.x] = idx[threadIdx.x];
    smc[threadIdx.x]  = mclip[b*NSEL + threadIdx.x];
  }
  __syncthreads();
  int r = h + (int)kk[(size_t)bh*WW + w];
  float sel[NSEL], prop[NSEL];
  float wmax = 0.0f;
  #pragma unroll
  for (int c=0;c<NSEL;c++) {
    const float* __restrict__ base = x + ((size_t)b*CC + sidx[c])*HW;
    sel[c]  = base[h*WW + w];
    prop[c] = base[r*WW + w];
    float v = fabsf(prop[c]-sel[c]) / smc[c];
    wmax = fmaxf(wmax, fminf(v, 1.0f));
  }
  #pragma unroll
  for (int c=0;c<NSEL;c++) {
    float rf = wmax*prop[c] + (1.0f - wmax)*sel[c];
    out[((size_t)b*CC + sidx[c])*HW + h*WW + w] = rf;
  }
}

extern "C" void kernel_launch(void* const* d_in, const int* in_sizes, int n_in,
                              void* d_out, int out_size, void* d_ws, size_t ws_size,
                              hipStream_t stream) {
  const float* x   = (const float*)d_in[0];
  const int* mask  = (const int*)d_in[1];
  float* out       = (float*)d_out;

  char* ws = (char*)d_ws;
  double* partials = (double*)(ws);                 // 1024*3*8 = 24576 B
  int*    idx      = (int*)(ws + 24576);            // 128 B
  float*  mclip    = (float*)(ws + 24576 + 128);    // 1024 B
  uint8_t* kk      = (uint8_t*)(ws + 24576 + 128 + 1024); // 245760 B

  k_copy_reduce<<<BB*CC, 256, 0, stream>>>(x, out, partials);
  k_select<<<1, CC, 0, stream>>>(partials, idx);
  k_runs<<<BB*5, 64, 0, stream>>>(mask, kk);
  k_maxdiff<<<BB*NSEL, 256, 0, stream>>>(x, idx, kk, mclip);
  k_refine<<<BB*HH, WW, 0, stream>>>(x, idx, kk, mclip, out);
}

// Round 3
// 100.447 us; speedup vs baseline: 1.3054x; 1.0296x over previous
//
#include <hip/hip_runtime.h>
#include <cstdint>
#include <cstddef>

#define BB 8
#define CC 128
#define HH 96
#define WW 320
#define HW (HH*WW)        // 30720
#define NSEL 32
#define NSELH 16
#define K1CH 2            // chunks per plane in K1
#define K4CH 8            // chunks per plane in K4

__device__ __forceinline__ float sigmoidf_(float x) {
  return __builtin_amdgcn_rcpf(1.0f + __expf(-x));
}

// K1: copy x -> out + per-(b,c,chunk) partial sums T, A, Q.
// Grid BB*CC*K1CH = 2048 blocks -> 8 blocks/CU -> 100% occupancy (MLP via TLP).
__global__ __launch_bounds__(256) void k_copy_reduce(
    const float* __restrict__ x, float* __restrict__ out,
    double* __restrict__ partials) {
  int t = threadIdx.x;
  int chunk = blockIdx.x & (K1CH-1);
  int bc = blockIdx.x >> 1;
  const float4* __restrict__ xi = (const float4*)(x + (size_t)bc * HW);
  float4* __restrict__ oi = (float4*)(out + (size_t)bc * HW);
  float tf = 0.0f, af = 0.0f, qf = 0.0f;
  // per chunk: 3840 float4 = 3 outer * 5 batch * 256 threads
  for (int outer = 0; outer < 3; ++outer) {
    int base = chunk*3840 + outer*1280;
    float4 v[5];
    #pragma unroll
    for (int u = 0; u < 5; u++) v[u] = xi[base + u*256 + t];
    #pragma unroll
    for (int u = 0; u < 5; u++) {
      int j = base + u*256 + t;
      oi[j] = v[u];
      int h = j / (WW/4);
      float d = 0.1f + (float)h * (0.9f/95.0f);
      float s0 = sigmoidf_(v[u].x), s1 = sigmoidf_(v[u].y);
      float s2 = sigmoidf_(v[u].z), s3 = sigmoidf_(v[u].w);
      float ts = (s0+s1)+(s2+s3);
      tf += ts;
      af += ts * d;
      qf += (s0*s0+s1*s1)+(s2*s2+s3*s3);
    }
  }
  __shared__ double sh[3][256];
  sh[0][t]=(double)tf; sh[1][t]=(double)af; sh[2][t]=(double)qf;
  __syncthreads();
  for (int ofs=128; ofs>0; ofs>>=1) {
    if (t < ofs) {
      sh[0][t]+=sh[0][t+ofs];
      sh[1][t]+=sh[1][t+ofs];
      sh[2][t]+=sh[2][t+ofs];
    }
    __syncthreads();
  }
  if (t==0) {
    int p = bc*K1CH + chunk;
    partials[p*3+0]=sh[0][0];
    partials[p*3+1]=sh[1][0];
    partials[p*3+2]=sh[2][0];
  }
}

// K2: reduce partials (fixed deterministic order), rank, emit idx[32].
__global__ __launch_bounds__(CC) void k_select(
    const double* __restrict__ partials, int* __restrict__ idx) {
  int c = threadIdx.x;
  double T=0.0, A=0.0, Q=0.0;
  for (int b=0;b<BB;b++) {
    for (int ch=0; ch<K1CH; ch++) {
      int p = (b*CC + c)*K1CH + ch;
      T += partials[p*3+0];
      A += partials[p*3+1];
      Q += partials[p*3+2];
    }
  }
  double sn = sqrt(Q); if (sn < 1e-6) sn = 1e-6;
  double c1 = A / sn;
  double c2 = (T - A) / sn;
  __shared__ double s1[CC], s2[CC];
  s1[c]=c1; s2[c]=c2;
  __syncthreads();
  int r1=0, r2=0;
  for (int j=0;j<CC;j++) {
    r1 += (s1[j] > c1) || (s1[j]==c1 && j<c);
    r2 += (s2[j] > c2) || (s2[j]==c2 && j<c);
  }
  if (r1 < NSELH) idx[r1] = c;
  if (r2 < NSELH) idx[NSELH + r2] = c;
}

// K3: closed-form runs via 96-bit column bitmask + ctz.
__global__ __launch_bounds__(64) void k_runs(
    const int* __restrict__ mask, uint8_t* __restrict__ kk) {
  int b = blockIdx.x / 5;
  int w = (blockIdx.x % 5)*64 + threadIdx.x;
  const int* __restrict__ mcol = mask + (size_t)b*HW + w;
  unsigned long long lo=0ull, hi=0ull;
  #pragma unroll
  for (int h=0; h<64; ++h) lo |= (unsigned long long)(mcol[h*WW]!=0) << h;
  #pragma unroll
  for (int h=64; h<95; ++h) hi |= (unsigned long long)(mcol[h*WW]!=0) << (h-64);
  uint8_t* __restrict__ kcol = kk + (size_t)b*HW + w;
  #pragma unroll
  for (int h=0; h<96; ++h) {
    unsigned long long s;
    if (h == 0)      s = lo;
    else if (h < 64) s = (lo >> h) | (hi << (64-h));
    else             s = hi >> (h-64);
    int run = __builtin_ctzll(~s | (1ull<<33));
    kcol[h*WW] = (uint8_t)(run > 32 ? 32 : run);
  }
}

// K4: per-(b,selc,chunk) partial max |prop-sel|. Grid BB*NSEL*K4CH = 2048.
__global__ __launch_bounds__(256) void k_maxdiff(
    const float* __restrict__ x, const int* __restrict__ idx,
    const uint8_t* __restrict__ kk, float* __restrict__ pmax) {
  int chunk = blockIdx.x & (K4CH-1);
  int bc32 = blockIdx.x >> 3;       // b*32 + c
  int b = bc32 >> 5;
  int c = bc32 & 31;
  int ic = idx[c];
  const float* __restrict__ base = x + ((size_t)b*CC + ic)*HW;
  const uint8_t* __restrict__ kb = kk + (size_t)b*HW;
  float mx = 0.0f;
  // per chunk: 960 float4 (HW/4/K4CH), stride 256 -> 3.75 iters
  int lo = chunk * (HW/4/K4CH), hiend = lo + (HW/4/K4CH);
  for (int j = lo + threadIdx.x; j < hiend; j += 256) {
    float4 sel = ((const float4*)base)[j];
    uchar4 kv  = ((const uchar4*)kb)[j];
    int h = j / (WW/4);
    int w4 = (j - h*(WW/4))*4;
    float p0 = base[(h+(int)kv.x)*WW + w4+0];
    float p1 = base[(h+(int)kv.y)*WW + w4+1];
    float p2 = base[(h+(int)kv.z)*WW + w4+2];
    float p3 = base[(h+(int)kv.w)*WW + w4+3];
    mx = fmaxf(mx, fmaxf(fmaxf(fabsf(p0-sel.x), fabsf(p1-sel.y)),
                         fmaxf(fabsf(p2-sel.z), fabsf(p3-sel.w))));
  }
  __shared__ float sh[256];
  sh[threadIdx.x]=mx; __syncthreads();
  for (int ofs=128; ofs>0; ofs>>=1) {
    if ((int)threadIdx.x<ofs) sh[threadIdx.x]=fmaxf(sh[threadIdx.x], sh[threadIdx.x+ofs]);
    __syncthreads();
  }
  if (threadIdx.x==0) pmax[blockIdx.x] = sh[0];
}

// K5: finalize mclip from chunk maxes, then
// w = max_c clip(|prop-sel|/mclip_c,0,1); refined = w*prop + (1-w)*sel.
__global__ __launch_bounds__(WW) void k_refine(
    const float* __restrict__ x, const int* __restrict__ idx,
    const uint8_t* __restrict__ kk, const float* __restrict__ pmax,
    float* __restrict__ out) {
  int bh = blockIdx.x;
  int b = bh / HH, h = bh - b*HH;
  int w = threadIdx.x;
  __shared__ int sidx[NSEL];
  __shared__ float smc[NSEL];
  if (threadIdx.x < NSEL) {
    int c = threadIdx.x;
    sidx[c] = idx[c];
    float m = 0.0f;
    #pragma unroll
    for (int ch=0; ch<K4CH; ch++) m = fmaxf(m, pmax[(b*NSEL + c)*K4CH + ch]);
    m *= 0.3f;
    if (m == 0.0f) m = 1.0f;
    smc[c] = m;
  }
  __syncthreads();
  int r = h + (int)kk[(size_t)bh*WW + w];
  float sel[NSEL], prop[NSEL];
  float wmax = 0.0f;
  #pragma unroll
  for (int c=0;c<NSEL;c++) {
    const float* __restrict__ base = x + ((size_t)b*CC + sidx[c])*HW;
    sel[c]  = base[h*WW + w];
    prop[c] = base[r*WW + w];
    float v = fabsf(prop[c]-sel[c]) / smc[c];
    wmax = fmaxf(wmax, fminf(v, 1.0f));
  }
  #pragma unroll
  for (int c=0;c<NSEL;c++) {
    float rf = wmax*prop[c] + (1.0f - wmax)*sel[c];
    out[((size_t)b*CC + sidx[c])*HW + h*WW + w] = rf;
  }
}

extern "C" void kernel_launch(void* const* d_in, const int* in_sizes, int n_in,
                              void* d_out, int out_size, void* d_ws, size_t ws_size,
                              hipStream_t stream) {
  const float* x   = (const float*)d_in[0];
  const int* mask  = (const int*)d_in[1];
  float* out       = (float*)d_out;

  char* ws = (char*)d_ws;
  double* partials = (double*)(ws);                       // 1024*2*3*8 = 49152 B
  int*    idx      = (int*)(ws + 49152);                  // 128 B
  float*  pmax     = (float*)(ws + 49152 + 128);          // 2048*4 = 8192 B
  uint8_t* kk      = (uint8_t*)(ws + 49152 + 128 + 8192); // 245760 B

  k_copy_reduce<<<BB*CC*K1CH, 256, 0, stream>>>(x, out, partials);
  k_select<<<1, CC, 0, stream>>>(partials, idx);
  k_runs<<<BB*5, 64, 0, stream>>>(mask, kk);
  k_maxdiff<<<BB*NSEL*K4CH, 256, 0, stream>>>(x, idx, kk, pmax);
  k_refine<<<BB*HH, WW, 0, stream>>>(x, idx, kk, pmax, out);
}